// Round 4
// baseline (54663.452 us; speedup 1.0000x reference)
//
#include <hip/hip_runtime.h>

#define NB    16      // batches
#define NPTS  100000  // points per batch
#define NCH   16      // channels
#define KSEL  1024    // samples
#define TPB   1024    // threads per fps block (one block per batch)
#define PPT   98      // ceil(NPTS / TPB)

// d_ws layout: [0, 65536) : idx list int[NB][KSEL]

__device__ __forceinline__ void combine(float ov, int oi, float& v, int& i) {
  if (ov > v || (ov == v && oi < i)) { v = ov; i = oi; }
}

// Full-grid read of points to pull the 102 MB input into L3 before fps starts.
__global__ void warm_kernel(const float4* __restrict__ p, float* __restrict__ sink) {
  const size_t n = (size_t)NB * NPTS * NCH / 4;
  float acc = 0.f;
  for (size_t i = (size_t)blockIdx.x * blockDim.x + threadIdx.x; i < n;
       i += (size_t)gridDim.x * blockDim.x) {
    const float4 v = p[i];
    acc += v.x + v.y + v.z + v.w;
  }
  if (acc == 123456.789f && (threadIdx.x & 1023) == 999)  // opaque, never-true in practice
    sink[0] = acc;
}

__global__ __launch_bounds__(TPB, 4)
void fps_kernel(const float* __restrict__ points, const int* __restrict__ start_idx,
                int* __restrict__ ws_idx) {
  const int b   = blockIdx.x;          // one block per batch
  const int tid = threadIdx.x;
  const int lane = tid & 63;
  const int wid  = tid >> 6;           // 16 waves

  const float* __restrict__ pb = points + (size_t)b * NPTS * NCH;

  // ---- load xyz into registers (float2 + float: no dead w register), init min_d ----
  float px[PPT], py[PPT], pz[PPT], md[PPT];
  #pragma unroll
  for (int k = 0; k < PPT; ++k) {
    const int li = tid + (k << 10);
    const bool valid = li < NPTS;
    float2 v2 = make_float2(0.f, 0.f);
    float  vz = 0.f;
    if (valid) {
      v2 = *reinterpret_cast<const float2*>(pb + (size_t)li * NCH);
      vz = pb[(size_t)li * NCH + 2];
    }
    px[k] = v2.x; py[k] = v2.y; pz[k] = vz;
    md[k] = valid ? __builtin_inff() : -__builtin_inff();
  }

  __shared__ float s_rv[2][16];   // parity-buffered block-reduce scratch
  __shared__ int   s_ri[2][16];

  // ---- initial selected point ----
  const int sidx = start_idx[b];
  float sx, sy, sz;
  {
    const float2 v2 = *reinterpret_cast<const float2*>(pb + (size_t)sidx * NCH);
    sx = v2.x; sy = v2.y; sz = pb[(size_t)sidx * NCH + 2];
  }
  if (tid == 0) ws_idx[b * KSEL] = sidx;

  for (int i = 0; i < KSEL - 1; ++i) {
    const int par = i & 1;

    // ---- distance update + thread-local argmax (bit-exact vs numpy f32:
    //      explicit IEEE intrinsics, left-to-right sum, no FMA contraction) ----
    float bv = -__builtin_inff();
    int   bi = 0x7fffffff;
    #pragma unroll
    for (int k = 0; k < PPT; ++k) {
      const float dx = __fsub_rn(px[k], sx);
      const float dy = __fsub_rn(py[k], sy);
      const float dz = __fsub_rn(pz[k], sz);
      const float d  = __fadd_rn(__fadd_rn(__fmul_rn(dx, dx), __fmul_rn(dy, dy)),
                                 __fmul_rn(dz, dz));
      const float m  = fminf(md[k], d);
      md[k] = m;
      if (m > bv) { bv = m; bi = tid + (k << 10); }  // k asc -> first-max kept
    }

    // ---- wave reduce (val, idx), first-index tie-break ----
    #pragma unroll
    for (int m = 32; m >= 1; m >>= 1) {
      const float ov = __shfl_xor(bv, m, 64);
      const int   oi = __shfl_xor(bi, m, 64);
      combine(ov, oi, bv, bi);
    }
    if (lane == 0) { s_rv[par][wid] = bv; s_ri[par][wid] = bi; }
    __syncthreads();                 // single barrier per iteration (parity protects scratch)

    // ---- block combine over 16 wave records (redundant on all threads) ----
    bv = s_rv[par][0]; bi = s_ri[par][0];
    #pragma unroll
    for (int w = 1; w < 16; ++w) combine(s_rv[par][w], s_ri[par][w], bv, bi);
    // (bv, bi) block-uniform; bi is the global point index within the batch

    if (tid == 0) ws_idx[b * KSEL + i + 1] = bi;

    // winner xyz: uniform load from points (L3-resident after warm kernel)
    const float2 v2 = *reinterpret_cast<const float2*>(pb + (size_t)bi * NCH);
    sx = v2.x; sy = v2.y; sz = pb[(size_t)bi * NCH + 2];
  }
}

__global__ void gather_kernel(const float* __restrict__ points,
                              const int* __restrict__ ws_idx,
                              float* __restrict__ out) {
  const int e = blockIdx.x * 256 + threadIdx.x;   // 0 .. NB*KSEL*NCH-1
  const int c = e & 15;
  const int k = (e >> 4) & (KSEL - 1);
  const int b = e >> 14;
  const int idx = ws_idx[b * KSEL + k];
  out[e] = points[((size_t)b * NPTS + idx) * NCH + c];
}

extern "C" void kernel_launch(void* const* d_in, const int* in_sizes, int n_in,
                              void* d_out, int out_size, void* d_ws, size_t ws_size,
                              hipStream_t stream) {
  const float* points    = (const float*)d_in[0];
  const int*   start_idx = (const int*)d_in[1];
  float*       out       = (float*)d_out;

  int*   idxl = (int*)d_ws;
  float* sink = (float*)((char*)d_ws + 65536);

  warm_kernel<<<2048, 256, 0, stream>>>(reinterpret_cast<const float4*>(points), sink);
  fps_kernel<<<NB, TPB, 0, stream>>>(points, start_idx, idxl);
  gather_kernel<<<(NB * KSEL * NCH) / 256, 256, 0, stream>>>(points, idxl, out);
}

// Round 5
// 4023.704 us; speedup vs baseline: 13.5854x; 13.5854x over previous
//
#include <hip/hip_runtime.h>

#define NB    16      // batches
#define NPTS  100000  // points per batch
#define NCH   16      // channels
#define KSEL  1024    // samples
#define SLOTS 16      // blocks per batch
#define TPB   256     // threads per block
#define CHUNK 6250    // NPTS / SLOTS
#define PPT   25      // CHUNK / TPB (ceil)

typedef unsigned long long u64;
#define SCOPE __HIP_MEMORY_SCOPE_AGENT

// d_ws layout (bytes):
//   [4096,  8192)   : cand u64[parity=2][NB][SLOTS]  (one 128B line per batch per parity)
//   [69632, 135168) : idx list int[NB][KSEL]
//
// Packed candidate word:
//   bits[63:32] = float bits of min_d value (>=0 -> bit order == float order)
//   bits[31:15] = 131071 - idx   (17 bits; larger == smaller idx -> first-index tie-break)
//   bits[14:5]  = tag = i+1      (1..1023, never 0 -> memset-0 never matches)
//   u64 max over slots == lexicographic (val desc, idx asc) winner.

__device__ __forceinline__ void combine(float ov, int oi, float& v, int& i) {
  if (ov > v || (ov == v && oi < i)) { v = ov; i = oi; }
}

__global__ __launch_bounds__(TPB, 1)
void fps_kernel(const float* __restrict__ points, const int* __restrict__ start_idx,
                u64* __restrict__ ws_cand, int* __restrict__ ws_idx) {
  // XCD-affinity swizzle: all 16 blocks of a batch on (likely) one XCD.
  const int raw  = blockIdx.x;
  const int xcd  = raw & 7;
  const int s    = raw >> 3;
  const int b    = xcd + 8 * (s >> 4);
  const int slot = s & 15;

  const int tid  = threadIdx.x;
  const int lane = tid & 63;
  const int wid  = tid >> 6;

  const int base = slot * CHUNK;
  const float* __restrict__ pb = points + (size_t)b * NPTS * NCH;

  // ---- load xyz into registers, init min_d ----
  float px[PPT], py[PPT], pz[PPT], md[PPT];
  #pragma unroll
  for (int k = 0; k < PPT; ++k) {
    const int li = tid + (k << 8);
    const bool valid = li < CHUNK;
    float4 p = make_float4(0.f, 0.f, 0.f, 0.f);
    if (valid) p = *reinterpret_cast<const float4*>(pb + (size_t)(base + li) * NCH);
    px[k] = p.x; py[k] = p.y; pz[k] = p.z;
    md[k] = valid ? __builtin_inff() : -__builtin_inff();
  }
  // PIN the point data in VGPRs. Without this, the register allocator
  // rematerializes the global loads inside the K-loop (round 3: VGPR=80 < the
  // 100 live floats), re-streaming 400KB/block/iter from L2 (~1.5us/iter).
  // The opaque asm makes each value's origin unknowable -> must stay live.
  // Budget: ~125 VGPR used, cap 512 at __launch_bounds__(256,1) -> no spill.
  #pragma unroll
  for (int k = 0; k < PPT; ++k)
    asm volatile("" : "+v"(px[k]), "+v"(py[k]), "+v"(pz[k]), "+v"(md[k]));

  __shared__ float s_rv[2][4];   // parity-buffered block-reduce scratch
  __shared__ int   s_ri[2][4];

  // ---- initial selected point ----
  const int sidx = start_idx[b];
  float sx, sy, sz;
  {
    const float4 p = *reinterpret_cast<const float4*>(pb + (size_t)sidx * NCH);
    sx = p.x; sy = p.y; sz = p.z;
  }
  if (slot == 0 && tid == 0) ws_idx[b * KSEL] = sidx;

  u64* const myrec = ws_cand + (size_t)b * SLOTS + slot;
  const u64* const cb0 = ws_cand + (size_t)b * SLOTS;

  for (int i = 0; i < KSEL - 1; ++i) {
    const int par = i & 1;
    const size_t poff = (size_t)par * NB * SLOTS;

    // ---- distance update + thread-local argmax (bit-exact vs numpy f32:
    //      explicit IEEE intrinsics, left-to-right sum, no FMA contraction) ----
    float bv = -__builtin_inff();
    int   bi = 0x7fffffff;
    #pragma unroll
    for (int k = 0; k < PPT; ++k) {
      const float dx = __fsub_rn(px[k], sx);
      const float dy = __fsub_rn(py[k], sy);
      const float dz = __fsub_rn(pz[k], sz);
      const float d  = __fadd_rn(__fadd_rn(__fmul_rn(dx, dx), __fmul_rn(dy, dy)),
                                 __fmul_rn(dz, dz));
      const float m  = fminf(md[k], d);
      md[k] = m;
      if (m > bv) { bv = m; bi = base + tid + (k << 8); }  // k asc -> first-max kept
    }

    // ---- wave reduce (val, idx), first-index tie-break ----
    #pragma unroll
    for (int m = 32; m >= 1; m >>= 1) {
      const float ov = __shfl_xor(bv, m, 64);
      const int   oi = __shfl_xor(bi, m, 64);
      combine(ov, oi, bv, bi);
    }
    if (lane == 0) { s_rv[par][wid] = bv; s_ri[par][wid] = bi; }
    __syncthreads();                       // the ONLY block barrier per iteration
    bv = s_rv[par][0]; bi = s_ri[par][0];
    #pragma unroll
    for (int w = 1; w < TPB / 64; ++w) combine(s_rv[par][w], s_ri[par][w], bv, bi);
    // (bv, bi) block-uniform

    // ---- publish: single relaxed 64-bit store ----
    const u64 key = ((u64)__float_as_uint(bv) << 32)
                  | ((u64)(unsigned)(131071 - bi) << 15)
                  | ((u64)(unsigned)(i + 1) << 5);
    if (tid == 0)
      __hip_atomic_store(myrec + poff, key, __ATOMIC_RELAXED, SCOPE);

    // ---- every wave polls all 16 slots (lane L owns slot L) ----
    const u64* cb = cb0 + poff;
    u64 w = 0;
    if (lane < SLOTS) {
      const unsigned want = (unsigned)(i + 1);
      do {
        w = __hip_atomic_load(cb + lane, __ATOMIC_RELAXED, SCOPE);
      } while ((unsigned)((w >> 5) & 0x3FF) != want);
    }
    // u64 max over 16 lanes (lanes >=16 hold 0)
    #pragma unroll
    for (int m = 8; m >= 1; m >>= 1) {
      const u64 o = __shfl_xor(w, m, 64);
      if (o > w) w = o;
    }
    w = __shfl(w, 0, 64);                  // broadcast winner to all lanes

    const int widx = 131071 - (int)((w >> 15) & 0x1FFFF);
    if (slot == 0 && tid == 0) ws_idx[b * KSEL + i + 1] = widx;

    // winner xyz from read-only points (L3-resident); uniform address per wave
    const float4 p = *reinterpret_cast<const float4*>(pb + (size_t)widx * NCH);
    sx = p.x; sy = p.y; sz = p.z;
  }
}

__global__ void gather_kernel(const float* __restrict__ points,
                              const int* __restrict__ ws_idx,
                              float* __restrict__ out) {
  const int e = blockIdx.x * TPB + threadIdx.x;   // 0 .. NB*KSEL*NCH-1
  const int c = e & 15;
  const int k = (e >> 4) & (KSEL - 1);
  const int b = e >> 14;
  const int idx = ws_idx[b * KSEL + k];
  out[e] = points[((size_t)b * NPTS + idx) * NCH + c];
}

extern "C" void kernel_launch(void* const* d_in, const int* in_sizes, int n_in,
                              void* d_out, int out_size, void* d_ws, size_t ws_size,
                              hipStream_t stream) {
  const float* points    = (const float*)d_in[0];
  const int*   start_idx = (const int*)d_in[1];
  float*       out       = (float*)d_out;

  u64* cand = (u64*)((char*)d_ws + 4096);
  int* idxl = (int*)((char*)d_ws + 4096 + 65536);

  // candidate tags must start at 0 every launch (graph-replay safe; tag 0 never expected)
  hipMemsetAsync(cand, 0, 2 * NB * SLOTS * sizeof(u64), stream);

  fps_kernel<<<NB * SLOTS, TPB, 0, stream>>>(points, start_idx, cand, idxl);
  gather_kernel<<<(NB * KSEL * NCH) / TPB, TPB, 0, stream>>>(points, idxl, out);
}

// Round 6
// 3720.503 us; speedup vs baseline: 14.6925x; 1.0815x over previous
//
#include <hip/hip_runtime.h>

#define NB    16      // batches
#define NPTS  100000  // points per batch
#define NCH   16      // channels
#define KSEL  1024    // samples
#define SLOTS 16      // blocks per batch
#define TPB   256     // threads per block
#define CHUNK 6250    // NPTS / SLOTS
#define PPT   25      // CHUNK / TPB (ceil)
#define MAGA  0x19u   // 5-bit magic, key words   (never 0, never 0xAA-pattern 01010/10101)
#define MAGB  0x13u   // 5-bit magic, payload words

typedef unsigned long long u64;
typedef unsigned int u32;

// d_ws layout (bytes):
//   [4096, 135168)  : cand u64[4][NB][256] — blk(tier,par,b), 2KB each:
//                     [0..63] recA keys, [64..255] recB payload (3 u64/slot)
//                     tier 0 = fast (sc0: per-XCD L2), tier 1 = slow (agent scope)
//   [135168, 200704): idx list int[NB][KSEL]
//
// Word formats (tag+magic in EVERY word -> stale/torn/poison self-rejecting):
//   key  = val_bits(32) | invidx(17) | tag(10) | MAGA(5)   (u64 max == winner)
//   wN   = coord_bits(32) | invidx(17) | tag(10) | MAGB(5)
// invidx = 131071 - idx  (max invidx == min idx -> first-index tie-break)
// Any tag-matched record is CORRECT: single writer per (slot,par,tag), and
// candidate values are deterministic functions of (slot, iteration) — identical
// across graph replays, so even a cross-replay stale line carries the right value.

__device__ __forceinline__ void combine(float ov, int oi, float& v, int& i) {
  if (ov > v || (ov == v && oi < i)) { v = ov; i = oi; }
}

// L2-tier store: bypass L1 (sc0), cached in this XCD's L2 (no sc1).
__device__ __forceinline__ void st_l2(u64* p, u64 v) {
  asm volatile("global_store_dwordx2 %0, %1, off sc0" :: "v"(p), "v"(v) : "memory");
}

__global__ __launch_bounds__(TPB, 1)
void fps_kernel(const float* __restrict__ points, const int* __restrict__ start_idx,
                u64* __restrict__ ws_cand, int* __restrict__ ws_idx) {
  // XCD-affinity swizzle: all 16 blocks of a batch at raw%8==const -> (likely) one XCD.
  const int raw  = blockIdx.x;
  const int xcd  = raw & 7;
  const int s    = raw >> 3;
  const int b    = xcd + 8 * (s >> 4);
  const int slot = s & 15;

  const int tid  = threadIdx.x;
  const int lane = tid & 63;
  const int wid  = tid >> 6;
  const int sid  = (slot << 2) | wid;   // wave-level slot id, 0..63

  const int base = slot * CHUNK;
  const float* __restrict__ pb = points + (size_t)b * NPTS * NCH;

  // ---- load xyz into registers, init min_d ----
  float px[PPT], py[PPT], pz[PPT], md[PPT];
  #pragma unroll
  for (int k = 0; k < PPT; ++k) {
    const int li = tid + (k << 8);
    const bool valid = li < CHUNK;
    float4 p = make_float4(0.f, 0.f, 0.f, 0.f);
    if (valid) p = *reinterpret_cast<const float4*>(pb + (size_t)(base + li) * NCH);
    px[k] = p.x; py[k] = p.y; pz[k] = p.z;
    md[k] = valid ? __builtin_inff() : -__builtin_inff();
  }
  #pragma unroll
  for (int k = 0; k < PPT; ++k)   // keep-live guard against remat (harmless)
    asm volatile("" : "+v"(px[k]), "+v"(py[k]), "+v"(pz[k]), "+v"(md[k]));

  // ---- initial selected point ----
  const int sidx = start_idx[b];
  float sx, sy, sz;
  {
    const float4 p = *reinterpret_cast<const float4*>(pb + (size_t)sidx * NCH);
    sx = p.x; sy = p.y; sz = p.z;
  }
  if (slot == 0 && tid == 0) ws_idx[b * KSEL] = sidx;

  for (int i = 0; i < KSEL - 1; ++i) {
    const int par = i & 1;
    u64* const fblk = ws_cand + (((size_t)par * NB + b) << 8);        // fast tier
    u64* const sblk = ws_cand + ((((size_t)2 + par) * NB + b) << 8);  // slow tier

    // ---- distance update + thread-local argmax (bit-exact vs numpy f32:
    //      IEEE intrinsics, left-to-right sum, no FMA contraction) ----
    float bv = -__builtin_inff();
    int   bi = 0x7fffffff;
    #pragma unroll
    for (int k = 0; k < PPT; ++k) {
      const float dx = __fsub_rn(px[k], sx);
      const float dy = __fsub_rn(py[k], sy);
      const float dz = __fsub_rn(pz[k], sz);
      const float d  = __fadd_rn(__fadd_rn(__fmul_rn(dx, dx), __fmul_rn(dy, dy)),
                                 __fmul_rn(dz, dz));
      const float m  = fminf(md[k], d);
      md[k] = m;
      if (m > bv) { bv = m; bi = base + tid + (k << 8); }  // k asc -> first-max kept
    }

    // ---- wave reduce (val, idx), first-index tie-break; all lanes get result ----
    #pragma unroll
    for (int m = 32; m >= 1; m >>= 1) {
      const float ov = __shfl_xor(bv, m, 64);
      const int   oi = __shfl_xor(bi, m, 64);
      combine(ov, oi, bv, bi);
    }

    // ---- owner lane publishes wave record to BOTH tiers (no barriers needed) ----
    const int local = bi - base;
    if (lane == (local & 63)) {
      const int kk = local >> 8;
      float ox = 0.f, oy = 0.f, oz = 0.f;
      #pragma unroll
      for (int k = 0; k < PPT; ++k)   // static-index select (keeps arrays in VGPRs)
        if (k == kk) { ox = px[k]; oy = py[k]; oz = pz[k]; }
      const u32 inv  = 131071u - (u32)bi;
      const u32 tm   = (u32)(i + 1) << 5;
      const u64 key  = ((u64)__float_as_uint(bv) << 32) | ((u64)(inv) << 15) | tm | MAGA;
      const u32 meta = (inv << 15) | tm | MAGB;
      const u64 w0 = ((u64)__float_as_uint(ox) << 32) | meta;
      const u64 w1 = ((u64)__float_as_uint(oy) << 32) | meta;
      const u64 w2 = ((u64)__float_as_uint(oz) << 32) | meta;
      st_l2(fblk + sid, key);
      st_l2(fblk + 64 + 3 * sid + 0, w0);
      st_l2(fblk + 64 + 3 * sid + 1, w1);
      st_l2(fblk + 64 + 3 * sid + 2, w2);
      __hip_atomic_store(sblk + sid,             key, __ATOMIC_RELAXED, __HIP_MEMORY_SCOPE_AGENT);
      __hip_atomic_store(sblk + 64 + 3 * sid + 0, w0, __ATOMIC_RELAXED, __HIP_MEMORY_SCOPE_AGENT);
      __hip_atomic_store(sblk + 64 + 3 * sid + 1, w1, __ATOMIC_RELAXED, __HIP_MEMORY_SCOPE_AGENT);
      __hip_atomic_store(sblk + 64 + 3 * sid + 2, w2, __ATOMIC_RELAXED, __HIP_MEMORY_SCOPE_AGENT);
    }

    // ---- poll: lane L owns slot L; fast tier first, slow tier after 2 retries ----
    const u32 wantA = ((u32)(i + 1) << 5) | MAGA;
    const u32 wantB = ((u32)(i + 1) << 5) | MAGB;
    u64* const pa  = fblk + lane;
    u64* const pb3 = fblk + 64 + 3 * lane;
    u64 ka = 0, q0 = 0, q1 = 0, q2 = 0;
    u32 need = 0xFu;
    int retry = 0;
    while (true) {
      u64 fa, f0, f1, f2;
      asm volatile(
        "global_load_dwordx2 %0, %4, off sc0\n\t"
        "global_load_dwordx2 %1, %5, off sc0\n\t"
        "global_load_dwordx2 %2, %6, off sc0\n\t"
        "global_load_dwordx2 %3, %7, off sc0\n\t"
        "s_waitcnt vmcnt(0)"
        : "=&v"(fa), "=&v"(f0), "=&v"(f1), "=&v"(f2)
        : "v"(pa), "v"(pb3), "v"(pb3 + 1), "v"(pb3 + 2)
        : "memory");
      if ((need & 1u) && ((u32)fa & 0x7FFFu) == wantA) { ka = fa; need &= ~1u; }
      if ((need & 2u) && ((u32)f0 & 0x7FFFu) == wantB) { q0 = f0; need &= ~2u; }
      if ((need & 4u) && ((u32)f1 & 0x7FFFu) == wantB) { q1 = f1; need &= ~4u; }
      if ((need & 8u) && ((u32)f2 & 0x7FFFu) == wantB) { q2 = f2; need &= ~8u; }
      if (!need) break;
      if (++retry >= 2) {   // coherent fallback (correct regardless of XCD mapping)
        const u64 va = __hip_atomic_load(sblk + lane,              __ATOMIC_RELAXED, __HIP_MEMORY_SCOPE_AGENT);
        const u64 v0 = __hip_atomic_load(sblk + 64 + 3 * lane,     __ATOMIC_RELAXED, __HIP_MEMORY_SCOPE_AGENT);
        const u64 v1 = __hip_atomic_load(sblk + 64 + 3 * lane + 1, __ATOMIC_RELAXED, __HIP_MEMORY_SCOPE_AGENT);
        const u64 v2 = __hip_atomic_load(sblk + 64 + 3 * lane + 2, __ATOMIC_RELAXED, __HIP_MEMORY_SCOPE_AGENT);
        if ((need & 1u) && ((u32)va & 0x7FFFu) == wantA) { ka = va; need &= ~1u; }
        if ((need & 2u) && ((u32)v0 & 0x7FFFu) == wantB) { q0 = v0; need &= ~2u; }
        if ((need & 4u) && ((u32)v1 & 0x7FFFu) == wantB) { q1 = v1; need &= ~4u; }
        if ((need & 8u) && ((u32)v2 & 0x7FFFu) == wantB) { q2 = v2; need &= ~8u; }
        if (!need) break;
      }
    }

    // ---- global winner: u64 max over 64 lanes; payload via shuffle from winner lane ----
    u64 kmax = ka;
    #pragma unroll
    for (int m = 32; m >= 1; m >>= 1) {
      const u64 o = __shfl_xor(kmax, m, 64);
      if (o > kmax) kmax = o;
    }
    const unsigned long long ball = __ballot(ka == kmax);  // keys unique (distinct idx)
    const int wl = __ffsll(ball) - 1;
    sx = __uint_as_float((u32)__shfl((int)(u32)(q0 >> 32), wl, 64));
    sy = __uint_as_float((u32)__shfl((int)(u32)(q1 >> 32), wl, 64));
    sz = __uint_as_float((u32)__shfl((int)(u32)(q2 >> 32), wl, 64));

    if (slot == 0 && tid == 0)
      ws_idx[b * KSEL + i + 1] = 131071 - (int)((kmax >> 15) & 0x1FFFFu);
  }
}

__global__ void gather_kernel(const float* __restrict__ points,
                              const int* __restrict__ ws_idx,
                              float* __restrict__ out) {
  const int e = blockIdx.x * TPB + threadIdx.x;   // 0 .. NB*KSEL*NCH-1
  const int c = e & 15;
  const int k = (e >> 4) & (KSEL - 1);
  const int b = e >> 14;
  const int idx = ws_idx[b * KSEL + k];
  out[e] = points[((size_t)b * NPTS + idx) * NCH + c];
}

extern "C" void kernel_launch(void* const* d_in, const int* in_sizes, int n_in,
                              void* d_out, int out_size, void* d_ws, size_t ws_size,
                              hipStream_t stream) {
  const float* points    = (const float*)d_in[0];
  const int*   start_idx = (const int*)d_in[1];
  float*       out       = (float*)d_out;

  u64* cand = (u64*)((char*)d_ws + 4096);
  int* idxl = (int*)((char*)d_ws + 4096 + 131072);

  // all record words must start tag-invalid (0) every launch (graph-replay safe)
  hipMemsetAsync(cand, 0, 131072, stream);

  fps_kernel<<<NB * SLOTS, TPB, 0, stream>>>(points, start_idx, cand, idxl);
  gather_kernel<<<(NB * KSEL * NCH) / TPB, TPB, 0, stream>>>(points, idxl, out);
}